// Round 22
// baseline (229.748 us; speedup 1.0000x reference)
//
#include <hip/hip_runtime.h>
#include <math.h>

#define BB  16
#define TT  1024
#define NN  128
#define WIN 30
#define NWD 498          // number of windows
#define DM  256          // D_MODEL
#define IND 384          // 3*N
#define GW  16           // windows per staging group in k24 (r17 optimum; alive-row span 62 <= 64)

#define INV_W (1.0f/498.0f)

#define SARR (BB*NN*NN)  // one b-major NxN array

// workspace offsets in floats
#define OFF_A     0                        // rstd/sqrt(29) per (b,w,ch); dead after k24
#define OFF_G     (OFF_A    + BB*NWD*NN)   // sqrt(30)*mu*a; dead after k24
#define OFF_CM2   (OFF_G    + BB*NWD*NN)
#define OFF_CM4   (OFF_CM2  + SARR)
#define OFF_CM8   (OFF_CM4  + SARR)
#define OFF_AD    (OFF_CM8  + SARR)        // 3 per-d rowcorr arrays, (b*3+d) major
#define OFF_PART  (OFF_AD   + 3*SARR)      // 768 slots x 16384 floats
// PART is fully consumed by kred before these are written -> alias:
#define OFF_ANORM OFF_PART
#define OFF_BUFA  (OFF_ANORM + SARR)
#define OFF_BUFB  (OFF_BUFA + BB*NN*DM)
#define OFF_AUX   (OFF_PART + 768*16384)   // [0,2048) rowsum[b*128+n], [2048,2064) head[b]
// GW1/SG/SB live PAST the A/G regions' live range: written by k1 extra blocks
// (before k24 reads A/G!) -> must NOT alias A. Place after AUX instead.
#define OFF_GW1   (OFF_AUX + 2064)         // 384*256
#define OFF_SG    (OFF_GW1 + IND*DM)       // 256
#define OFF_SB    (OFF_SG  + DM)           // 256

// async global->LDS 16B/lane (wave-uniform LDS base + lane*16)
#define GLL16(gsrc, ldst) \
    __builtin_amdgcn_global_load_lds((const __attribute__((address_space(1))) void*)(gsrc), \
                                     (__attribute__((address_space(3))) void*)(ldst), 16, 0, 0)

// ---------------------------------------------------------------- K1: sliding per-window channel stats (+ AUX zeroing)
// Extra blocks 256..352 precompute GW1 = gamma*W1, SG, SB (overlaps k24 in the pipeline).
__global__ __launch_bounds__(128) void k1_stats(const float* __restrict__ x,
                                                const float* __restrict__ gamma, const float* __restrict__ beta,
                                                const float* __restrict__ W1, float* __restrict__ ws) {
    int bx = blockIdx.x;
    int tid = threadIdx.x;
    if (bx >= 256) {
        int gi = bx - 256;
        if (gi < 96) {
#pragma unroll
            for (int kk = 0; kk < 4; ++kk) {
                int k = gi*4 + kk;
                for (int c = tid; c < DM; c += 128)
                    ws[OFF_GW1 + (size_t)k*DM + c] = gamma[k] * W1[(size_t)k*DM + c];
            }
        } else {
            for (int c = tid; c < DM; c += 128) {
                float sgv = 0.f, sbv = 0.f;
                for (int k = 0; k < IND; ++k) {
                    float w = W1[(size_t)k*DM + c];
                    sgv = fmaf(gamma[k], w, sgv);
                    sbv = fmaf(beta[k],  w, sbv);
                }
                ws[OFF_SG + c] = sgv;
                ws[OFF_SB + c] = sbv;
            }
        }
        return;
    }
    if (bx == 0) {
        for (int i = tid; i < 2064; i += 128) ws[OFF_AUX + i] = 0.f;
    }
    int c = bx & 15, b = bx >> 4;
    int w0 = c*32, w1 = min(NWD, w0+32);
    int n = tid;
    const float* xp = x + (size_t)b*TT*NN + n;

    float sum = 0.f, sq = 0.f;
    for (int t = 2*w0; t < 2*w0 + WIN; ++t) {
        float v = xp[(size_t)t*NN];
        sum += v; sq = fmaf(v, v, sq);
    }
    for (int w = w0; w < w1; ++w) {
        if (w > w0) {
            float o0 = xp[(size_t)(2*w-2)*NN], o1 = xp[(size_t)(2*w-1)*NN];
            float n0 = xp[(size_t)(2*w+28)*NN], n1 = xp[(size_t)(2*w+29)*NN];
            sum += (n0 + n1) - (o0 + o1);
            sq  += (n0*n0 + n1*n1) - (o0*o0 + o1*o1);
        }
        float mean = sum * (1.0f/30.0f);
        float ss = sq - 30.0f*mean*mean;
        float var = fmaxf(ss * (1.0f/29.0f), 1e-8f);
        float a = (1.0f / sqrtf(var)) * 0.185695338f;   // fold 1/sqrt(29)
        ws[OFF_A + ((size_t)b*NWD + w)*NN + n] = a;
        ws[OFF_G + ((size_t)b*NWD + w)*NN + n] = mean * a * 5.477225575f;   // sqrt(30)*mu*a
    }
}

// ---------------------------------------------------------------- K24: incremental sliding cross-products (r17-proven config)
__global__ __launch_bounds__(256) __attribute__((amdgpu_waves_per_eu(3, 3)))
void k24_inc(const float* __restrict__ x, float* __restrict__ ws) {
    __shared__ __align__(16) float xr[64][NN];   // circular x-row buffer (32 KB)
    __shared__ __align__(16) float sa[GW][NN];   // 8 KB
    __shared__ __align__(16) float sg[GW][NN];   // 8 KB
    int bx = blockIdx.x;
    int wc = bx & 7;
    int slab = (bx >> 3) % 6;
    int b = bx / 48;
    const char IS[6] = {0,0,0,0,1,1};
    const char JS[6] = {0,1,2,3,2,3};
    int is = IS[slab], js = JS[slab];
    int w0 = wc * 63, w1 = min(NWD, w0 + 63);
    int tid = threadIdx.x;
    int jg = tid & 7, ig = tid >> 3;
    int i0 = is*64 + ig*2;
    int j0 = js*32 + jg*4;

    const float* xb = x + (size_t)b*TT*NN;
    const float* Ab = ws + OFF_A + (size_t)b*NWD*NN;
    const float* Gb = ws + OFF_G + (size_t)b*NWD*NN;

    float P[2][4];
    float S1[2][4], S2[2][4], S3[2][4], S4[2][4], S5[2][4], S6[2][4], S7[2][4], S8[2][4];
#pragma unroll
    for (int p=0;p<2;++p)
#pragma unroll
        for (int q=0;q<4;++q) {
            P[p][q]=0.f;
            S1[p][q]=0.f;S2[p][q]=0.f;S3[p][q]=0.f;S4[p][q]=0.f;
            S5[p][q]=0.f;S6[p][q]=0.f;S7[p][q]=0.f;S8[p][q]=0.f;
        }

    auto moments = [&](int k) {
        float2 ai = *(const float2*)&sa[k][i0];
        float2 gi = *(const float2*)&sg[k][i0];
        float4 aj = *(const float4*)&sa[k][j0];
        float4 gj = *(const float4*)&sg[k][j0];
        float av[2] = {ai.x, ai.y};
        float mg[2] = {-gi.x, -gi.y};
        float aw[4] = {aj.x, aj.y, aj.z, aj.w};
        float gw[4] = {gj.x, gj.y, gj.z, gj.w};
#pragma unroll
        for (int p=0;p<2;++p)
#pragma unroll
            for (int q=0;q<4;++q) {
                float aa  = av[p]*aw[q];
                float ngg = mg[p]*gw[q];
                float c   = fmaf(P[p][q], aa, ngg);
                float c2 = c*c;
                float c3 = c2*c;
                float c4 = c2*c2;
                S1[p][q] += c;
                S2[p][q] += c2;
                S3[p][q] += c3;
                S4[p][q] += c4;
                S5[p][q] = fmaf(c4, c,  S5[p][q]);
                S6[p][q] = fmaf(c3, c3, S6[p][q]);
                S7[p][q] = fmaf(c3, c4, S7[p][q]);
                S8[p][q] = fmaf(c4, c4, S8[p][q]);
            }
    };

    int rlo = 2*w0;                 // first row not yet staged
    for (int wg = w0; wg < w1; wg += GW) {
        int m = min(GW, w1 - wg);
        __syncthreads();            // prior group's compute done reading xr/sa/sg
        int rhi = 2*(wg + m - 1) + 29;
        int nr = rhi - rlo + 1;
        for (int idx = tid; idx < nr*32; idx += 256) {
            int r = idx >> 5, c4 = idx & 31;
            int t = rlo + r;
            GLL16(xb + (size_t)t*NN + c4*4, &xr[t & 63][c4*4]);
        }
        for (int idx = tid; idx < m*32; idx += 256) {
            int k = idx >> 5, c4 = idx & 31;
            GLL16(Ab + (size_t)(wg+k)*NN + c4*4, &sa[k][c4*4]);
        }
        for (int idx = tid; idx < m*32; idx += 256) {
            int k = idx >> 5, c4 = idx & 31;
            GLL16(Gb + (size_t)(wg+k)*NN + c4*4, &sg[k][c4*4]);
        }
        rlo = rhi + 1;
        __syncthreads();            // drains vmcnt -> staging visible

        int kstart = 0;
        if (wg == w0) {
#pragma unroll 6
            for (int k = 0; k < WIN; ++k) {
                int t = 2*w0 + k;
                float2 xi = *(const float2*)&xr[t & 63][i0];
                float4 xj = *(const float4*)&xr[t & 63][j0];
                float av[2] = {xi.x, xi.y};
                float bv[4] = {xj.x, xj.y, xj.z, xj.w};
#pragma unroll
                for (int p=0;p<2;++p)
#pragma unroll
                    for (int q=0;q<4;++q) P[p][q] = fmaf(av[p], bv[q], P[p][q]);
            }
            moments(0);
            kstart = 1;
        }
        for (int k = kstart; k < m; ++k) {
            int w = wg + k;
            int tr[4] = {2*w - 2, 2*w - 1, 2*w + 28, 2*w + 29};
#pragma unroll
            for (int kk = 0; kk < 4; ++kk) {
                int t = tr[kk];
                float sgn = (kk < 2) ? -1.0f : 1.0f;
                float2 xi = *(const float2*)&xr[t & 63][i0];
                float4 xj = *(const float4*)&xr[t & 63][j0];
                float av[2] = {sgn*xi.x, sgn*xi.y};
                float bv[4] = {xj.x, xj.y, xj.z, xj.w};
#pragma unroll
                for (int p=0;p<2;++p)
#pragma unroll
                    for (int q=0;q<4;++q) P[p][q] = fmaf(av[p], bv[q], P[p][q]);
            }
            moments(k);
        }
    }

    float* tp = ws + OFF_PART + (size_t)bx*16384 + tid*8;
#define STORE_ARR(A, S) \
    *(float4*)&tp[(A)*2048]     = make_float4(S[0][0], S[0][1], S[0][2], S[0][3]); \
    *(float4*)&tp[(A)*2048 + 4] = make_float4(S[1][0], S[1][1], S[1][2], S[1][3]);
    STORE_ARR(0, S1) STORE_ARR(1, S2) STORE_ARR(2, S3) STORE_ARR(3, S4)
    STORE_ARR(4, S5) STORE_ARR(5, S6) STORE_ARR(6, S7) STORE_ARR(7, S8)
#undef STORE_ARR
}

// ---------------------------------------------------------------- Kred: reduce 8 chunk-partials -> centered moments
// Pure 192-block float4-vectorized reduction (GW1/SG/SB moved to k1).
__global__ __launch_bounds__(256) void kred(float* __restrict__ ws) {
    int bxg = blockIdx.x;
    int tid = threadIdx.x;
    int pair = bxg >> 1, half = bxg & 1;
    int b = pair / 6, slab = pair % 6;
    const char IS[6] = {0,0,0,0,1,1};
    const char JS[6] = {0,1,2,3,2,3};
    int is = IS[slab], js = JS[slab];
    int off4 = half*256 + tid;                // 0..511 float4-slots per slab
    const float4* base = (const float4*)(ws + OFF_PART + (size_t)(b*48 + slab*8)*16384);

    float4 E[8];
#pragma unroll
    for (int a=0;a<8;++a) E[a] = make_float4(0.f,0.f,0.f,0.f);
    for (int c = 0; c < 8; ++c) {
        const float4* tp = base + (size_t)c*4096;
#pragma unroll
        for (int a=0;a<8;++a) {
            float4 v = tp[a*512 + off4];
            E[a].x += v.x; E[a].y += v.y; E[a].z += v.z; E[a].w += v.w;
        }
    }
    float Es[8][4];
#pragma unroll
    for (int a=0;a<8;++a) { Es[a][0]=E[a].x; Es[a][1]=E[a].y; Es[a][2]=E[a].z; Es[a][3]=E[a].w; }

    // element decode (r17 PART layout): off = off4*4 + l; tid_old = off4>>1; e = (off4&1)*4 + l
    int tid_old = off4 >> 1, p = off4 & 1;
    int ig = tid_old >> 3, jg = tid_old & 7;
    int i  = is*64 + ig*2 + p;
    int j0 = js*32 + jg*4;
    float* C2 = ws + OFF_CM2 + (size_t)b*NN*NN;
    float* C4 = ws + OFF_CM4 + (size_t)b*NN*NN;
    float* C8 = ws + OFF_CM8 + (size_t)b*NN*NN;
#pragma unroll
    for (int l = 0; l < 4; ++l) {
        int j = j0 + l;
        float cm2, cm4, cm8;
        if (i == j) {
            cm2 = 0.f; cm4 = 0.f; cm8 = 0.f;
        } else {
            float e1 = Es[0][l]*INV_W, e2 = Es[1][l]*INV_W, e3 = Es[2][l]*INV_W, e4 = Es[3][l]*INV_W;
            float e5 = Es[4][l]*INV_W, e6 = Es[5][l]*INV_W, e7 = Es[6][l]*INV_W, e8 = Es[7][l]*INV_W;
            float m  = e1;
            float m2 = m*m, m3 = m2*m, m4 = m2*m2, m5 = m4*m, m6 = m3*m3, m8 = m4*m4;
            cm2 = e2 - m2;
            cm4 = e4 - 4.f*m*e3 + 6.f*m2*e2 - 3.f*m4;
            cm8 = e8 - 8.f*m*e7 + 28.f*m2*e6 - 56.f*m3*e5 + 70.f*m4*e4
                     - 56.f*m5*e3 + 28.f*m6*e2 - 7.f*m8;
        }
        C2[i*NN + j] = cm2; C2[j*NN + i] = cm2;
        C4[i*NN + j] = cm4; C4[j*NN + i] = cm4;
        C8[i*NN + j] = cm8; C8[j*NN + i] = cm8;
    }
}

// ---------------------------------------------------------------- KB: merged k5 rowwise_corr (0..191) | k78' LN-folded gemm1 (192..703)
// NO same-kernel cross-block reads: k5 blocks contribute row sums via device atomics.
#define XSTR 132   // transposed row stride
__global__ __launch_bounds__(256) void kB(const float* __restrict__ b1, float* __restrict__ ws) {
    __shared__ __align__(16) float smem[64*XSTR + 2*NN];   // 34.8 KB (k5 view)
    int blk = blockIdx.x, tid = threadIdx.x;
    if (blk < 192) {
        // ---- k5: (b, di, j-quarter); 8x2 tiles over 128 x 32, f in two halves
        int rem = blk % 12;
        int b = blk / 12, di = rem >> 2, jq = rem & 3;
        float* Xct = smem;                  // [64][XSTR] f-major (transposed half)
        float* Mr  = smem + 64*XSTR;        // [128] row means
        float* Ir  = Mr + NN;               // [128] row inv-dens
        const float* cm = ws + (di==0 ? OFF_CM2 : (di==1 ? OFF_CM4 : OFF_CM8)) + (size_t)b*NN*NN;
        int n0 = (tid >> 4)*8, m0 = jq*32 + (tid & 15)*2;
        float s1 = 0.f, s2 = 0.f;
        float acc0[8], acc1[8];
#pragma unroll
        for (int k=0;k<8;++k) { acc0[k]=0.f; acc1[k]=0.f; }

        for (int h = 0; h < 2; ++h) {
            __syncthreads();
            for (int idx = tid; idx < NN*64; idx += 256) {
                int n = idx >> 6, f0 = idx & 63;
                Xct[f0*XSTR + n] = cm[n*NN + h*64 + f0];
            }
            __syncthreads();
            if (tid < NN) {
                for (int f0 = 0; f0 < 64; ++f0) {
                    float v = Xct[f0*XSTR + tid];
                    s1 += v; s2 = fmaf(v, v, s2);
                }
            }
            for (int f0 = 0; f0 < 64; ++f0) {
                const float* row = &Xct[f0*XSTR];
                float4 a0 = *(const float4*)&row[n0];
                float4 a1 = *(const float4*)&row[n0+4];
                float2 bm = *(const float2*)&row[m0];
                float av[8] = {a0.x,a0.y,a0.z,a0.w,a1.x,a1.y,a1.z,a1.w};
#pragma unroll
                for (int k=0;k<8;++k) {
                    acc0[k] = fmaf(av[k], bm.x, acc0[k]);
                    acc1[k] = fmaf(av[k], bm.y, acc1[k]);
                }
            }
        }
        __syncthreads();
        if (tid < NN) {
            float mean = s1 * (1.0f/NN);
            Mr[tid] = mean;
            Ir[tid] = 1.0f/sqrtf(fmaxf(s2 - (float)NN*mean*mean, 1e-8f));
        }
        __syncthreads();
        float rm0 = Mr[m0], rm1 = Mr[m0+1], im0 = Ir[m0], im1 = Ir[m0+1];
        float* Ad = ws + OFF_AD + (size_t)(b*3 + di)*NN*NN;
        float* rowsum = ws + OFF_AUX + (size_t)b*NN;
        int l = tid & 15;
#pragma unroll
        for (int k=0;k<8;++k) {
            int gi = n0+k;
            float rn = Mr[gi], inv = Ir[gi];
            float v0 = (acc0[k] - (float)NN*rn*rm0) * inv * im0;
            float v1 = (acc1[k] - (float)NN*rn*rm1) * inv * im1;
            if (gi == m0)   v0 = 1.0f;
            if (gi == m0+1) v1 = 1.0f;
            Ad[gi*NN + m0]     = v0;
            Ad[gi*NN + m0 + 1] = v1;
            float s = v0 + v1;
#pragma unroll
            for (int o = 8; o > 0; o >>= 1) s += __shfl_down(s, o, 16);
            if (l == 0) atomicAdd(&rowsum[gi], s * (1.0f/3.0f));
        }
    } else {
        // ---- k78': 4 rows/block, LDS-free gemm via GW1/SG/SB
        int r0 = (blk - 192) * 4;
        float* sms = smem;
        float* srs = smem + 4;
        {
            int rloc = tid >> 6, lane = tid & 63;
            int grow = r0 + rloc;
            int b = grow >> 7, n = grow & 127;
            const float* c2 = ws + OFF_CM2 + ((size_t)b*NN + n)*NN;
            const float* c4 = ws + OFF_CM4 + ((size_t)b*NN + n)*NN;
            const float* c8 = ws + OFF_CM8 + ((size_t)b*NN + n)*NN;
            float s1 = 0.f, s2 = 0.f;
            for (int e = lane; e < IND; e += 64) {
                float v = (e < 128) ? c2[e] : (e < 256) ? c4[e-128] : c8[e-256];
                s1 += v; s2 = fmaf(v, v, s2);
            }
#pragma unroll
            for (int o = 32; o > 0; o >>= 1) {
                s1 += __shfl_down(s1, o, 64);
                s2 += __shfl_down(s2, o, 64);
            }
            if (lane == 0) {
                float mean = s1 * (1.0f/IND);
                sms[rloc] = mean;
                srs[rloc] = 1.0f / sqrtf(s2*(1.0f/IND) - mean*mean + 1e-5f);
            }
        }
        __syncthreads();
        float mean[4], rstd[4];
        const float* xrow[4];
#pragma unroll
        for (int r = 0; r < 4; ++r) {
            mean[r] = sms[r]; rstd[r] = srs[r];
        }
        float acc[4] = {0.f, 0.f, 0.f, 0.f};
        const float* GW1p = ws + OFF_GW1;
#pragma unroll
        for (int seg = 0; seg < 3; ++seg) {
            int offc = (seg==0) ? OFF_CM2 : (seg==1) ? OFF_CM4 : OFF_CM8;
#pragma unroll
            for (int r = 0; r < 4; ++r) {
                int grow = r0 + r;
                xrow[r] = ws + offc + ((size_t)(grow >> 7)*NN + (grow & 127))*NN;
            }
            const float* gseg = GW1p + (size_t)(seg*128)*DM + tid;
            for (int k = 0; k < 128; k += 2) {
                float g0 = gseg[(size_t)(k+0)*DM];
                float g1 = gseg[(size_t)(k+1)*DM];
#pragma unroll
                for (int r = 0; r < 4; ++r) {
                    acc[r] = fmaf(xrow[r][k+0], g0, acc[r]);
                    acc[r] = fmaf(xrow[r][k+1], g1, acc[r]);
                }
            }
        }
        float sgv = ws[OFF_SG + tid];
        float sbb = ws[OFF_SB + tid] + b1[tid];
        float* O = ws + OFF_BUFA;
#pragma unroll
        for (int r = 0; r < 4; ++r)
            O[(size_t)(r0+r)*DM + tid] = rstd[r]*(acc[r] - mean[r]*sgv) + sbb;
    }
}

// ---------------------------------------------------------------- K6: normalize adjacency (cross-kernel reads only)
__global__ __launch_bounds__(256) void k6_anorm(float* __restrict__ ws) {
    __shared__ float dis[NN];
    int b = blockIdx.x, tid = threadIdx.x;
    const float* rowsum = ws + OFF_AUX + (size_t)b*NN;
    if (tid < NN) {
        float d = 1.0f + rowsum[tid];       // +I diag; rowsum includes Abar row (diag=1)
        dis[tid] = sqrtf(1.0f / fmaxf(d, 1e-8f));
    }
    __syncthreads();
    const float* A0 = ws + OFF_AD + (size_t)(b*3 + 0)*NN*NN;
    const float* A1 = ws + OFF_AD + (size_t)(b*3 + 1)*NN*NN;
    const float* A2 = ws + OFF_AD + (size_t)(b*3 + 2)*NN*NN;
    float* An = ws + OFF_ANORM + (size_t)b*NN*NN;
    for (int idx = tid; idx < NN*NN; idx += 256) {
        int n = idx >> 7, m = idx & 127;
        float s = (A0[idx] + A1[idx] + A2[idx]) * (1.0f/3.0f);
        float v = s + (n==m ? 1.0f : 0.0f);
        An[idx] = v * dis[n] * dis[m];
    }
}

// ---------------------------------------------------------------- K98: fused H=relu(An@M1); M2 = H@W2+b2 (4 rows/block)
__global__ __launch_bounds__(256) void k98_propgemm(const float* __restrict__ W2, const float* __restrict__ b2,
                                                    const float* __restrict__ An, const float* __restrict__ Zin,
                                                    float* __restrict__ Out) {
    __shared__ float Hs[4][DM];
    int bx = blockIdx.x;
    int b = bx >> 5, n0 = (bx & 31)*4;
    int tid = threadIdx.x;
    const float* A = An + (size_t)b*NN*NN + (size_t)n0*NN;
    const float* Z = Zin + (size_t)b*NN*DM;
    float acc[4] = {0,0,0,0};
    for (int m = 0; m < NN; m += 4) {
        float z0 = Z[(size_t)(m+0)*DM + tid];
        float z1 = Z[(size_t)(m+1)*DM + tid];
        float z2 = Z[(size_t)(m+2)*DM + tid];
        float z3 = Z[(size_t)(m+3)*DM + tid];
#pragma unroll
        for (int r = 0; r < 4; ++r) {
            const float* Ar = A + r*NN + m;     // uniform address -> s_load
            acc[r] = fmaf(Ar[0], z0, acc[r]);
            acc[r] = fmaf(Ar[1], z1, acc[r]);
            acc[r] = fmaf(Ar[2], z2, acc[r]);
            acc[r] = fmaf(Ar[3], z3, acc[r]);
        }
    }
#pragma unroll
    for (int r = 0; r < 4; ++r) Hs[r][tid] = fmaxf(acc[r], 0.0f);
    __syncthreads();
    float acc2[4];
    float bv = b2[tid];
#pragma unroll
    for (int r = 0; r < 4; ++r) acc2[r] = bv;
    for (int k = 0; k < DM; k += 4) {
        float w0 = W2[(size_t)(k+0)*DM + tid];
        float w1 = W2[(size_t)(k+1)*DM + tid];
        float w2 = W2[(size_t)(k+2)*DM + tid];
        float w3 = W2[(size_t)(k+3)*DM + tid];
#pragma unroll
        for (int r = 0; r < 4; ++r) {
            float4 h = *(const float4*)&Hs[r][k];
            acc2[r] = fmaf(h.x, w0, acc2[r]);
            acc2[r] = fmaf(h.y, w1, acc2[r]);
            acc2[r] = fmaf(h.z, w2, acc2[r]);
            acc2[r] = fmaf(h.w, w3, acc2[r]);
        }
    }
    float* O = Out + (size_t)b*NN*DM;
#pragma unroll
    for (int r = 0; r < 4; ++r) O[(size_t)(n0+r)*DM + tid] = acc2[r];
}

// ---------------------------------------------------------------- K9: H2 = relu(An@M2); head partial via coherence-point atomic
__global__ __launch_bounds__(256) void k9_prop(const float* __restrict__ Wc,
                                               const float* __restrict__ An, const float* __restrict__ Zin,
                                               float* __restrict__ ws) {
    __shared__ float red[256];
    int bx = blockIdx.x;
    int b = bx >> 5, n0 = (bx & 31)*4;
    int tid = threadIdx.x;
    const float* A = An + (size_t)b*NN*NN + (size_t)n0*NN;
    const float* Z = Zin + (size_t)b*NN*DM;
    float acc[4] = {0,0,0,0};
    for (int m = 0; m < NN; m += 4) {
        float z0 = Z[(size_t)(m+0)*DM + tid];
        float z1 = Z[(size_t)(m+1)*DM + tid];
        float z2 = Z[(size_t)(m+2)*DM + tid];
        float z3 = Z[(size_t)(m+3)*DM + tid];
#pragma unroll
        for (int r = 0; r < 4; ++r) {
            const float* Ar = A + r*NN + m;     // uniform address -> s_load
            acc[r] = fmaf(Ar[0], z0, acc[r]);
            acc[r] = fmaf(Ar[1], z1, acc[r]);
            acc[r] = fmaf(Ar[2], z2, acc[r]);
            acc[r] = fmaf(Ar[3], z3, acc[r]);
        }
    }
    float hsum = fmaxf(acc[0], 0.0f) + fmaxf(acc[1], 0.0f)
               + fmaxf(acc[2], 0.0f) + fmaxf(acc[3], 0.0f);
    red[tid] = hsum * Wc[tid];
    __syncthreads();
    for (int o = 128; o > 0; o >>= 1) { if (tid < o) red[tid] += red[tid+o]; __syncthreads(); }
    if (tid == 0) atomicAdd(ws + OFF_AUX + 2048 + b, red[0]);
}

// ---------------------------------------------------------------- K12: sigmoid head (cross-kernel read)
__global__ __launch_bounds__(64) void k12_head(const float* __restrict__ bc,
                                               const float* __restrict__ ws, float* __restrict__ outp) {
    int tid = threadIdx.x;
    if (tid < BB) {
        float g = ws[OFF_AUX + 2048 + tid] * (1.0f/NN);
        outp[tid] = 1.0f/(1.0f + expf(-(g + bc[0])));
    }
}

// ----------------------------------------------------------------
extern "C" void kernel_launch(void* const* d_in, const int* in_sizes, int n_in,
                              void* d_out, int out_size, void* d_ws, size_t ws_size,
                              hipStream_t stream) {
    (void)in_sizes; (void)n_in; (void)out_size; (void)ws_size;
    const float* x     = (const float*)d_in[0];
    const float* gamma = (const float*)d_in[1];
    const float* beta  = (const float*)d_in[2];
    const float* W1    = (const float*)d_in[3];
    const float* b1    = (const float*)d_in[4];
    const float* W2    = (const float*)d_in[5];
    const float* b2    = (const float*)d_in[6];
    const float* Wc    = (const float*)d_in[7];
    const float* bc    = (const float*)d_in[8];
    float* ws  = (float*)d_ws;
    float* out = (float*)d_out;

    k1_stats    <<<256+96+1, 128, 0, stream>>>(x, gamma, beta, W1, ws);
    k24_inc     <<<BB*6*8,   256, 0, stream>>>(x, ws);
    kred        <<<192,      256, 0, stream>>>(ws);
    kB          <<<704,      256, 0, stream>>>(b1, ws);
    k6_anorm    <<<BB,       256, 0, stream>>>(ws);
    k98_propgemm<<<BB*32,    256, 0, stream>>>(W2, b2, ws + OFF_ANORM, ws + OFF_BUFA, ws + OFF_BUFB);
    k9_prop     <<<BB*32,    256, 0, stream>>>(Wc, ws + OFF_ANORM, ws + OFF_BUFB, ws);
    k12_head    <<<1,        64,  0, stream>>>(bc, ws, out);
}

// Round 23
// 223.040 us; speedup vs baseline: 1.0301x; 1.0301x over previous
//
#include <hip/hip_runtime.h>
#include <math.h>

#define BB  16
#define TT  1024
#define NN  128
#define WIN 30
#define NWD 498          // number of windows
#define DM  256          // D_MODEL
#define IND 384          // 3*N
#define GW  16           // windows per staging group in k24 (r17 optimum; alive-row span 62 <= 64)

#define INV_W (1.0f/498.0f)

#define SARR (BB*NN*NN)  // one b-major NxN array

// workspace offsets in floats
#define OFF_A     0                        // rstd/sqrt(29) per (b,w,ch); dead after k24
#define OFF_G     (OFF_A    + BB*NWD*NN)   // sqrt(30)*mu*a; dead after k24
#define OFF_CM2   (OFF_G    + BB*NWD*NN)
#define OFF_CM4   (OFF_CM2  + SARR)
#define OFF_CM8   (OFF_CM4  + SARR)
#define OFF_AD    (OFF_CM8  + SARR)        // 3 per-d rowcorr arrays, (b*3+d) major
#define OFF_PART  (OFF_AD   + 3*SARR)      // 768 slots x 16384 floats
// PART is fully consumed by kred before these are written -> alias:
#define OFF_ANORM OFF_PART
#define OFF_BUFA  (OFF_ANORM + SARR)
#define OFF_BUFB  (OFF_BUFA + BB*NN*DM)
#define OFF_AUX   (OFF_PART + 768*16384)   // [0,2048) rowsum[b*128+n], [2048,2064) head[b]
// GW1/SG/SB alias the dead A region (written by kred extra blocks, read by kB)
#define OFF_GW1   OFF_A                    // 384*256
#define OFF_SG    (OFF_GW1 + IND*DM)       // 256
#define OFF_SB    (OFF_SG  + DM)           // 256

// async global->LDS 16B/lane (wave-uniform LDS base + lane*16)
#define GLL16(gsrc, ldst) \
    __builtin_amdgcn_global_load_lds((const __attribute__((address_space(1))) void*)(gsrc), \
                                     (__attribute__((address_space(3))) void*)(ldst), 16, 0, 0)

// ---------------------------------------------------------------- K1: sliding per-window channel stats (+ AUX zeroing)
__global__ __launch_bounds__(128) void k1_stats(const float* __restrict__ x, float* __restrict__ ws) {
    int bx = blockIdx.x;
    if (bx == 0) {
        for (int i = threadIdx.x; i < 2064; i += 128) ws[OFF_AUX + i] = 0.f;
    }
    int c = bx & 15, b = bx >> 4;
    int w0 = c*32, w1 = min(NWD, w0+32);
    int n = threadIdx.x;
    const float* xp = x + (size_t)b*TT*NN + n;

    float sum = 0.f, sq = 0.f;
    for (int t = 2*w0; t < 2*w0 + WIN; ++t) {
        float v = xp[(size_t)t*NN];
        sum += v; sq = fmaf(v, v, sq);
    }
    for (int w = w0; w < w1; ++w) {
        if (w > w0) {
            float o0 = xp[(size_t)(2*w-2)*NN], o1 = xp[(size_t)(2*w-1)*NN];
            float n0 = xp[(size_t)(2*w+28)*NN], n1 = xp[(size_t)(2*w+29)*NN];
            sum += (n0 + n1) - (o0 + o1);
            sq  += (n0*n0 + n1*n1) - (o0*o0 + o1*o1);
        }
        float mean = sum * (1.0f/30.0f);
        float ss = sq - 30.0f*mean*mean;
        float var = fmaxf(ss * (1.0f/29.0f), 1e-8f);
        float a = (1.0f / sqrtf(var)) * 0.185695338f;   // fold 1/sqrt(29)
        ws[OFF_A + ((size_t)b*NWD + w)*NN + n] = a;
        ws[OFF_G + ((size_t)b*NWD + w)*NN + n] = mean * a * 5.477225575f;   // sqrt(30)*mu*a
    }
}

// ---------------------------------------------------------------- K24: incremental sliding cross-products (r17-proven config)
__global__ __launch_bounds__(256) __attribute__((amdgpu_waves_per_eu(3, 3)))
void k24_inc(const float* __restrict__ x, float* __restrict__ ws) {
    __shared__ __align__(16) float xr[64][NN];   // circular x-row buffer (32 KB)
    __shared__ __align__(16) float sa[GW][NN];   // 8 KB
    __shared__ __align__(16) float sg[GW][NN];   // 8 KB
    int bx = blockIdx.x;
    int wc = bx & 7;
    int slab = (bx >> 3) % 6;
    int b = bx / 48;
    const char IS[6] = {0,0,0,0,1,1};
    const char JS[6] = {0,1,2,3,2,3};
    int is = IS[slab], js = JS[slab];
    int w0 = wc * 63, w1 = min(NWD, w0 + 63);
    int tid = threadIdx.x;
    int jg = tid & 7, ig = tid >> 3;
    int i0 = is*64 + ig*2;
    int j0 = js*32 + jg*4;

    const float* xb = x + (size_t)b*TT*NN;
    const float* Ab = ws + OFF_A + (size_t)b*NWD*NN;
    const float* Gb = ws + OFF_G + (size_t)b*NWD*NN;

    float P[2][4];
    float S1[2][4], S2[2][4], S3[2][4], S4[2][4], S5[2][4], S6[2][4], S7[2][4], S8[2][4];
#pragma unroll
    for (int p=0;p<2;++p)
#pragma unroll
        for (int q=0;q<4;++q) {
            P[p][q]=0.f;
            S1[p][q]=0.f;S2[p][q]=0.f;S3[p][q]=0.f;S4[p][q]=0.f;
            S5[p][q]=0.f;S6[p][q]=0.f;S7[p][q]=0.f;S8[p][q]=0.f;
        }

    auto moments = [&](int k) {
        float2 ai = *(const float2*)&sa[k][i0];
        float2 gi = *(const float2*)&sg[k][i0];
        float4 aj = *(const float4*)&sa[k][j0];
        float4 gj = *(const float4*)&sg[k][j0];
        float av[2] = {ai.x, ai.y};
        float mg[2] = {-gi.x, -gi.y};
        float aw[4] = {aj.x, aj.y, aj.z, aj.w};
        float gw[4] = {gj.x, gj.y, gj.z, gj.w};
#pragma unroll
        for (int p=0;p<2;++p)
#pragma unroll
            for (int q=0;q<4;++q) {
                float aa  = av[p]*aw[q];
                float ngg = mg[p]*gw[q];
                float c   = fmaf(P[p][q], aa, ngg);
                float c2 = c*c;
                float c3 = c2*c;
                float c4 = c2*c2;
                S1[p][q] += c;
                S2[p][q] += c2;
                S3[p][q] += c3;
                S4[p][q] += c4;
                S5[p][q] = fmaf(c4, c,  S5[p][q]);
                S6[p][q] = fmaf(c3, c3, S6[p][q]);
                S7[p][q] = fmaf(c3, c4, S7[p][q]);
                S8[p][q] = fmaf(c4, c4, S8[p][q]);
            }
    };

    int rlo = 2*w0;                 // first row not yet staged
    for (int wg = w0; wg < w1; wg += GW) {
        int m = min(GW, w1 - wg);
        __syncthreads();            // prior group's compute done reading xr/sa/sg
        int rhi = 2*(wg + m - 1) + 29;
        int nr = rhi - rlo + 1;
        for (int idx = tid; idx < nr*32; idx += 256) {
            int r = idx >> 5, c4 = idx & 31;
            int t = rlo + r;
            GLL16(xb + (size_t)t*NN + c4*4, &xr[t & 63][c4*4]);
        }
        for (int idx = tid; idx < m*32; idx += 256) {
            int k = idx >> 5, c4 = idx & 31;
            GLL16(Ab + (size_t)(wg+k)*NN + c4*4, &sa[k][c4*4]);
        }
        for (int idx = tid; idx < m*32; idx += 256) {
            int k = idx >> 5, c4 = idx & 31;
            GLL16(Gb + (size_t)(wg+k)*NN + c4*4, &sg[k][c4*4]);
        }
        rlo = rhi + 1;
        __syncthreads();            // drains vmcnt -> staging visible

        int kstart = 0;
        if (wg == w0) {
#pragma unroll 6
            for (int k = 0; k < WIN; ++k) {
                int t = 2*w0 + k;
                float2 xi = *(const float2*)&xr[t & 63][i0];
                float4 xj = *(const float4*)&xr[t & 63][j0];
                float av[2] = {xi.x, xi.y};
                float bv[4] = {xj.x, xj.y, xj.z, xj.w};
#pragma unroll
                for (int p=0;p<2;++p)
#pragma unroll
                    for (int q=0;q<4;++q) P[p][q] = fmaf(av[p], bv[q], P[p][q]);
            }
            moments(0);
            kstart = 1;
        }
        for (int k = kstart; k < m; ++k) {
            int w = wg + k;
            int tr[4] = {2*w - 2, 2*w - 1, 2*w + 28, 2*w + 29};
#pragma unroll
            for (int kk = 0; kk < 4; ++kk) {
                int t = tr[kk];
                float sgn = (kk < 2) ? -1.0f : 1.0f;
                float2 xi = *(const float2*)&xr[t & 63][i0];
                float4 xj = *(const float4*)&xr[t & 63][j0];
                float av[2] = {sgn*xi.x, sgn*xi.y};
                float bv[4] = {xj.x, xj.y, xj.z, xj.w};
#pragma unroll
                for (int p=0;p<2;++p)
#pragma unroll
                    for (int q=0;q<4;++q) P[p][q] = fmaf(av[p], bv[q], P[p][q]);
            }
            moments(k);
        }
    }

    float* tp = ws + OFF_PART + (size_t)bx*16384 + tid*8;
#define STORE_ARR(A, S) \
    *(float4*)&tp[(A)*2048]     = make_float4(S[0][0], S[0][1], S[0][2], S[0][3]); \
    *(float4*)&tp[(A)*2048 + 4] = make_float4(S[1][0], S[1][1], S[1][2], S[1][3]);
    STORE_ARR(0, S1) STORE_ARR(1, S2) STORE_ARR(2, S3) STORE_ARR(3, S4)
    STORE_ARR(4, S5) STORE_ARR(5, S6) STORE_ARR(6, S7) STORE_ARR(7, S8)
#undef STORE_ARR
}

// ---------------------------------------------------------------- Kred: reduce 8 chunk-partials -> centered moments
// float4-vectorized loads: 192 main blocks (half-slab each); extras 192.. do GW1/SG/SB.
__global__ __launch_bounds__(256) void kred(const float* __restrict__ gamma, const float* __restrict__ beta,
                                            const float* __restrict__ W1, float* __restrict__ ws) {
    int bxg = blockIdx.x;
    int tid = threadIdx.x;
    if (bxg >= 192) {
        int gi = bxg - 192;
        if (gi < 96) {
#pragma unroll
            for (int kk = 0; kk < 4; ++kk) {
                int k = gi*4 + kk;
                ws[OFF_GW1 + (size_t)k*DM + tid] = gamma[k] * W1[(size_t)k*DM + tid];
            }
        } else {
            float sgv = 0.f, sbv = 0.f;
            for (int k = 0; k < IND; ++k) {
                float w = W1[(size_t)k*DM + tid];
                sgv = fmaf(gamma[k], w, sgv);
                sbv = fmaf(beta[k],  w, sbv);
            }
            ws[OFF_SG + tid] = sgv;
            ws[OFF_SB + tid] = sbv;
        }
        return;
    }
    int pair = bxg >> 1, half = bxg & 1;
    int b = pair / 6, slab = pair % 6;
    const char IS[6] = {0,0,0,0,1,1};
    const char JS[6] = {0,1,2,3,2,3};
    int is = IS[slab], js = JS[slab];
    int off4 = half*256 + tid;                // 0..511 float4-slots per slab
    const float4* base = (const float4*)(ws + OFF_PART + (size_t)(b*48 + slab*8)*16384);

    float4 E[8];
#pragma unroll
    for (int a=0;a<8;++a) E[a] = make_float4(0.f,0.f,0.f,0.f);
    for (int c = 0; c < 8; ++c) {
        const float4* tp = base + (size_t)c*4096;
#pragma unroll
        for (int a=0;a<8;++a) {
            float4 v = tp[a*512 + off4];
            E[a].x += v.x; E[a].y += v.y; E[a].z += v.z; E[a].w += v.w;
        }
    }
    float Es[8][4];
#pragma unroll
    for (int a=0;a<8;++a) { Es[a][0]=E[a].x; Es[a][1]=E[a].y; Es[a][2]=E[a].z; Es[a][3]=E[a].w; }

    // element decode (r17 PART layout): off = off4*4 + l; tid_old = off4>>1; e = (off4&1)*4 + l
    int tid_old = off4 >> 1, p = off4 & 1;
    int ig = tid_old >> 3, jg = tid_old & 7;
    int i  = is*64 + ig*2 + p;
    int j0 = js*32 + jg*4;
    float* C2 = ws + OFF_CM2 + (size_t)b*NN*NN;
    float* C4 = ws + OFF_CM4 + (size_t)b*NN*NN;
    float* C8 = ws + OFF_CM8 + (size_t)b*NN*NN;
#pragma unroll
    for (int l = 0; l < 4; ++l) {
        int j = j0 + l;
        float cm2, cm4, cm8;
        if (i == j) {
            cm2 = 0.f; cm4 = 0.f; cm8 = 0.f;
        } else {
            float e1 = Es[0][l]*INV_W, e2 = Es[1][l]*INV_W, e3 = Es[2][l]*INV_W, e4 = Es[3][l]*INV_W;
            float e5 = Es[4][l]*INV_W, e6 = Es[5][l]*INV_W, e7 = Es[6][l]*INV_W, e8 = Es[7][l]*INV_W;
            float m  = e1;
            float m2 = m*m, m3 = m2*m, m4 = m2*m2, m5 = m4*m, m6 = m3*m3, m8 = m4*m4;
            cm2 = e2 - m2;
            cm4 = e4 - 4.f*m*e3 + 6.f*m2*e2 - 3.f*m4;
            cm8 = e8 - 8.f*m*e7 + 28.f*m2*e6 - 56.f*m3*e5 + 70.f*m4*e4
                     - 56.f*m5*e3 + 28.f*m6*e2 - 7.f*m8;
        }
        C2[i*NN + j] = cm2; C2[j*NN + i] = cm2;
        C4[i*NN + j] = cm4; C4[j*NN + i] = cm4;
        C8[i*NN + j] = cm8; C8[j*NN + i] = cm8;
    }
}

// ---------------------------------------------------------------- KB: merged k5 rowwise_corr (0..191) | k78' LN-folded gemm1 (192..703)
// NO same-kernel cross-block reads: k5 blocks contribute row sums via device atomics.
#define XSTR 132   // transposed row stride
__global__ __launch_bounds__(256) void kB(const float* __restrict__ b1, float* __restrict__ ws) {
    __shared__ __align__(16) float smem[64*XSTR + 2*NN];   // 34.8 KB (k5 view)
    int blk = blockIdx.x, tid = threadIdx.x;
    if (blk < 192) {
        // ---- k5: (b, di, j-quarter); 8x2 tiles over 128 x 32, f in two halves
        int rem = blk % 12;
        int b = blk / 12, di = rem >> 2, jq = rem & 3;
        float* Xct = smem;                  // [64][XSTR] f-major (transposed half)
        float* Mr  = smem + 64*XSTR;        // [128] row means
        float* Ir  = Mr + NN;               // [128] row inv-dens
        const float* cm = ws + (di==0 ? OFF_CM2 : (di==1 ? OFF_CM4 : OFF_CM8)) + (size_t)b*NN*NN;
        int n0 = (tid >> 4)*8, m0 = jq*32 + (tid & 15)*2;
        float s1 = 0.f, s2 = 0.f;
        float acc0[8], acc1[8];
#pragma unroll
        for (int k=0;k<8;++k) { acc0[k]=0.f; acc1[k]=0.f; }

        for (int h = 0; h < 2; ++h) {
            __syncthreads();
            for (int idx = tid; idx < NN*64; idx += 256) {
                int n = idx >> 6, f0 = idx & 63;
                Xct[f0*XSTR + n] = cm[n*NN + h*64 + f0];
            }
            __syncthreads();
            if (tid < NN) {
                for (int f0 = 0; f0 < 64; ++f0) {
                    float v = Xct[f0*XSTR + tid];
                    s1 += v; s2 = fmaf(v, v, s2);
                }
            }
            for (int f0 = 0; f0 < 64; ++f0) {
                const float* row = &Xct[f0*XSTR];
                float4 a0 = *(const float4*)&row[n0];
                float4 a1 = *(const float4*)&row[n0+4];
                float2 bm = *(const float2*)&row[m0];
                float av[8] = {a0.x,a0.y,a0.z,a0.w,a1.x,a1.y,a1.z,a1.w};
#pragma unroll
                for (int k=0;k<8;++k) {
                    acc0[k] = fmaf(av[k], bm.x, acc0[k]);
                    acc1[k] = fmaf(av[k], bm.y, acc1[k]);
                }
            }
        }
        __syncthreads();
        if (tid < NN) {
            float mean = s1 * (1.0f/NN);
            Mr[tid] = mean;
            Ir[tid] = 1.0f/sqrtf(fmaxf(s2 - (float)NN*mean*mean, 1e-8f));
        }
        __syncthreads();
        float rm0 = Mr[m0], rm1 = Mr[m0+1], im0 = Ir[m0], im1 = Ir[m0+1];
        float* Ad = ws + OFF_AD + (size_t)(b*3 + di)*NN*NN;
        float* rowsum = ws + OFF_AUX + (size_t)b*NN;
        int l = tid & 15;
#pragma unroll
        for (int k=0;k<8;++k) {
            int gi = n0+k;
            float rn = Mr[gi], inv = Ir[gi];
            float v0 = (acc0[k] - (float)NN*rn*rm0) * inv * im0;
            float v1 = (acc1[k] - (float)NN*rn*rm1) * inv * im1;
            if (gi == m0)   v0 = 1.0f;
            if (gi == m0+1) v1 = 1.0f;
            Ad[gi*NN + m0]     = v0;
            Ad[gi*NN + m0 + 1] = v1;
            float s = v0 + v1;
#pragma unroll
            for (int o = 8; o > 0; o >>= 1) s += __shfl_down(s, o, 16);
            if (l == 0) atomicAdd(&rowsum[gi], s * (1.0f/3.0f));
        }
    } else {
        // ---- k78': 4 rows/block, LDS-free gemm via GW1/SG/SB
        int r0 = (blk - 192) * 4;
        float* sms = smem;
        float* srs = smem + 4;
        {
            int rloc = tid >> 6, lane = tid & 63;
            int grow = r0 + rloc;
            int b = grow >> 7, n = grow & 127;
            const float* c2 = ws + OFF_CM2 + ((size_t)b*NN + n)*NN;
            const float* c4 = ws + OFF_CM4 + ((size_t)b*NN + n)*NN;
            const float* c8 = ws + OFF_CM8 + ((size_t)b*NN + n)*NN;
            float s1 = 0.f, s2 = 0.f;
            for (int e = lane; e < IND; e += 64) {
                float v = (e < 128) ? c2[e] : (e < 256) ? c4[e-128] : c8[e-256];
                s1 += v; s2 = fmaf(v, v, s2);
            }
#pragma unroll
            for (int o = 32; o > 0; o >>= 1) {
                s1 += __shfl_down(s1, o, 64);
                s2 += __shfl_down(s2, o, 64);
            }
            if (lane == 0) {
                float mean = s1 * (1.0f/IND);
                sms[rloc] = mean;
                srs[rloc] = 1.0f / sqrtf(s2*(1.0f/IND) - mean*mean + 1e-5f);
            }
        }
        __syncthreads();
        float mean[4], rstd[4];
        const float* xrow[4];
#pragma unroll
        for (int r = 0; r < 4; ++r) {
            mean[r] = sms[r]; rstd[r] = srs[r];
        }
        float acc[4] = {0.f, 0.f, 0.f, 0.f};
        const float* GW1p = ws + OFF_GW1;
#pragma unroll
        for (int seg = 0; seg < 3; ++seg) {
            int offc = (seg==0) ? OFF_CM2 : (seg==1) ? OFF_CM4 : OFF_CM8;
#pragma unroll
            for (int r = 0; r < 4; ++r) {
                int grow = r0 + r;
                xrow[r] = ws + offc + ((size_t)(grow >> 7)*NN + (grow & 127))*NN;
            }
            const float* gseg = GW1p + (size_t)(seg*128)*DM + tid;
            for (int k = 0; k < 128; k += 2) {
                float g0 = gseg[(size_t)(k+0)*DM];
                float g1 = gseg[(size_t)(k+1)*DM];
#pragma unroll
                for (int r = 0; r < 4; ++r) {
                    acc[r] = fmaf(xrow[r][k+0], g0, acc[r]);
                    acc[r] = fmaf(xrow[r][k+1], g1, acc[r]);
                }
            }
        }
        float sgv = ws[OFF_SG + tid];
        float sbb = ws[OFF_SB + tid] + b1[tid];
        float* O = ws + OFF_BUFA;
#pragma unroll
        for (int r = 0; r < 4; ++r)
            O[(size_t)(r0+r)*DM + tid] = rstd[r]*(acc[r] - mean[r]*sgv) + sbb;
    }
}

// ---------------------------------------------------------------- K6: normalize adjacency (cross-kernel reads only)
__global__ __launch_bounds__(256) void k6_anorm(float* __restrict__ ws) {
    __shared__ float dis[NN];
    int b = blockIdx.x, tid = threadIdx.x;
    const float* rowsum = ws + OFF_AUX + (size_t)b*NN;
    if (tid < NN) {
        float d = 1.0f + rowsum[tid];       // +I diag; rowsum includes Abar row (diag=1)
        dis[tid] = sqrtf(1.0f / fmaxf(d, 1e-8f));
    }
    __syncthreads();
    const float* A0 = ws + OFF_AD + (size_t)(b*3 + 0)*NN*NN;
    const float* A1 = ws + OFF_AD + (size_t)(b*3 + 1)*NN*NN;
    const float* A2 = ws + OFF_AD + (size_t)(b*3 + 2)*NN*NN;
    float* An = ws + OFF_ANORM + (size_t)b*NN*NN;
    for (int idx = tid; idx < NN*NN; idx += 256) {
        int n = idx >> 7, m = idx & 127;
        float s = (A0[idx] + A1[idx] + A2[idx]) * (1.0f/3.0f);
        float v = s + (n==m ? 1.0f : 0.0f);
        An[idx] = v * dis[n] * dis[m];
    }
}

// ---------------------------------------------------------------- K98: fused H=relu(An@M1); M2 = H@W2+b2 (4 rows/block)
__global__ __launch_bounds__(256) void k98_propgemm(const float* __restrict__ W2, const float* __restrict__ b2,
                                                    const float* __restrict__ An, const float* __restrict__ Zin,
                                                    float* __restrict__ Out) {
    __shared__ float Hs[4][DM];
    int bx = blockIdx.x;
    int b = bx >> 5, n0 = (bx & 31)*4;
    int tid = threadIdx.x;
    const float* A = An + (size_t)b*NN*NN + (size_t)n0*NN;
    const float* Z = Zin + (size_t)b*NN*DM;
    float acc[4] = {0,0,0,0};
    for (int m = 0; m < NN; m += 4) {
        float z0 = Z[(size_t)(m+0)*DM + tid];
        float z1 = Z[(size_t)(m+1)*DM + tid];
        float z2 = Z[(size_t)(m+2)*DM + tid];
        float z3 = Z[(size_t)(m+3)*DM + tid];
#pragma unroll
        for (int r = 0; r < 4; ++r) {
            const float* Ar = A + r*NN + m;     // uniform address -> s_load
            acc[r] = fmaf(Ar[0], z0, acc[r]);
            acc[r] = fmaf(Ar[1], z1, acc[r]);
            acc[r] = fmaf(Ar[2], z2, acc[r]);
            acc[r] = fmaf(Ar[3], z3, acc[r]);
        }
    }
#pragma unroll
    for (int r = 0; r < 4; ++r) Hs[r][tid] = fmaxf(acc[r], 0.0f);
    __syncthreads();
    float acc2[4];
    float bv = b2[tid];
#pragma unroll
    for (int r = 0; r < 4; ++r) acc2[r] = bv;
    for (int k = 0; k < DM; k += 4) {
        float w0 = W2[(size_t)(k+0)*DM + tid];
        float w1 = W2[(size_t)(k+1)*DM + tid];
        float w2 = W2[(size_t)(k+2)*DM + tid];
        float w3 = W2[(size_t)(k+3)*DM + tid];
#pragma unroll
        for (int r = 0; r < 4; ++r) {
            float4 h = *(const float4*)&Hs[r][k];
            acc2[r] = fmaf(h.x, w0, acc2[r]);
            acc2[r] = fmaf(h.y, w1, acc2[r]);
            acc2[r] = fmaf(h.z, w2, acc2[r]);
            acc2[r] = fmaf(h.w, w3, acc2[r]);
        }
    }
    float* O = Out + (size_t)b*NN*DM;
#pragma unroll
    for (int r = 0; r < 4; ++r) O[(size_t)(n0+r)*DM + tid] = acc2[r];
}

// ---------------------------------------------------------------- K9: H2 = relu(An@M2); head partial via coherence-point atomic
__global__ __launch_bounds__(256) void k9_prop(const float* __restrict__ Wc,
                                               const float* __restrict__ An, const float* __restrict__ Zin,
                                               float* __restrict__ ws) {
    __shared__ float red[256];
    int bx = blockIdx.x;
    int b = bx >> 5, n0 = (bx & 31)*4;
    int tid = threadIdx.x;
    const float* A = An + (size_t)b*NN*NN + (size_t)n0*NN;
    const float* Z = Zin + (size_t)b*NN*DM;
    float acc[4] = {0,0,0,0};
    for (int m = 0; m < NN; m += 4) {
        float z0 = Z[(size_t)(m+0)*DM + tid];
        float z1 = Z[(size_t)(m+1)*DM + tid];
        float z2 = Z[(size_t)(m+2)*DM + tid];
        float z3 = Z[(size_t)(m+3)*DM + tid];
#pragma unroll
        for (int r = 0; r < 4; ++r) {
            const float* Ar = A + r*NN + m;     // uniform address -> s_load
            acc[r] = fmaf(Ar[0], z0, acc[r]);
            acc[r] = fmaf(Ar[1], z1, acc[r]);
            acc[r] = fmaf(Ar[2], z2, acc[r]);
            acc[r] = fmaf(Ar[3], z3, acc[r]);
        }
    }
    float hsum = fmaxf(acc[0], 0.0f) + fmaxf(acc[1], 0.0f)
               + fmaxf(acc[2], 0.0f) + fmaxf(acc[3], 0.0f);
    red[tid] = hsum * Wc[tid];
    __syncthreads();
    for (int o = 128; o > 0; o >>= 1) { if (tid < o) red[tid] += red[tid+o]; __syncthreads(); }
    if (tid == 0) atomicAdd(ws + OFF_AUX + 2048 + b, red[0]);
}

// ---------------------------------------------------------------- K12: sigmoid head (cross-kernel read)
__global__ __launch_bounds__(64) void k12_head(const float* __restrict__ bc,
                                               const float* __restrict__ ws, float* __restrict__ outp) {
    int tid = threadIdx.x;
    if (tid < BB) {
        float g = ws[OFF_AUX + 2048 + tid] * (1.0f/NN);
        outp[tid] = 1.0f/(1.0f + expf(-(g + bc[0])));
    }
}

// ----------------------------------------------------------------
extern "C" void kernel_launch(void* const* d_in, const int* in_sizes, int n_in,
                              void* d_out, int out_size, void* d_ws, size_t ws_size,
                              hipStream_t stream) {
    (void)in_sizes; (void)n_in; (void)out_size; (void)ws_size;
    const float* x     = (const float*)d_in[0];
    const float* gamma = (const float*)d_in[1];
    const float* beta  = (const float*)d_in[2];
    const float* W1    = (const float*)d_in[3];
    const float* b1    = (const float*)d_in[4];
    const float* W2    = (const float*)d_in[5];
    const float* b2    = (const float*)d_in[6];
    const float* Wc    = (const float*)d_in[7];
    const float* bc    = (const float*)d_in[8];
    float* ws  = (float*)d_ws;
    float* out = (float*)d_out;

    k1_stats    <<<BB*16,    128, 0, stream>>>(x, ws);
    k24_inc     <<<BB*6*8,   256, 0, stream>>>(x, ws);
    kred        <<<192+96+1, 256, 0, stream>>>(gamma, beta, W1, ws);
    kB          <<<704,      256, 0, stream>>>(b1, ws);
    k6_anorm    <<<BB,       256, 0, stream>>>(ws);
    k98_propgemm<<<BB*32,    256, 0, stream>>>(W2, b2, ws + OFF_ANORM, ws + OFF_BUFA, ws + OFF_BUFB);
    k9_prop     <<<BB*32,    256, 0, stream>>>(Wc, ws + OFF_ANORM, ws + OFF_BUFB, ws);
    k12_head    <<<1,        64,  0, stream>>>(bc, ws, out);
}